// Round 2
// baseline (144.136 us; speedup 1.0000x reference)
//
#include <hip/hip_runtime.h>
#include <math.h>
#include <stdint.h>

#define N_NODES 8192
#define D 7
#define K 32
#define NT 256
#define Q 4              // queries per block
#define CPT 32           // candidates per thread = N_NODES / NT
#define HALF 16          // first half stored in registers; second half streamed
#define CAPQ 512         // per-query candidate capacity (expected M ~ 60-110)

__device__ __forceinline__ float rfl(float v) {
    return __uint_as_float(__builtin_amdgcn_readfirstlane(__float_as_uint(v)));
}

// ---------------------------------------------------------------------------
// Kernel 1: out = clip(feat @ W^T, -1, 1), sq = rowsum(feat^2)
// ---------------------------------------------------------------------------
__global__ __launch_bounds__(NT)
void precompute_kernel(const float* __restrict__ x, const float* __restrict__ W,
                       float* __restrict__ outb, float* __restrict__ sqb)
{
    int n = blockIdx.x * NT + threadIdx.x;
    float4 v0 = *reinterpret_cast<const float4*>(x + n * 8);
    float4 v1 = *reinterpret_cast<const float4*>(x + n * 8 + 4);
    float f[D] = {v0.x, v0.y, v0.z, v0.w, v1.x, v1.y, v1.z};
    float sq = 0.f;
#pragma unroll
    for (int c = 0; c < D; ++c) sq += f[c] * f[c];
    sqb[n] = sq;
#pragma unroll
    for (int r = 0; r < D; ++r) {
        float acc = 0.f;
#pragma unroll
        for (int c = 0; c < D; ++c) acc += f[c] * W[r * D + c];
        acc = fminf(fmaxf(acc, -1.f), 1.f);
        outb[n * D + r] = acc;
    }
}

// ---------------------------------------------------------------------------
// Kernel 2: exact top-32 (jax.lax.top_k order) + attention. Q=4 queries/block.
// ---------------------------------------------------------------------------
__global__ __launch_bounds__(NT)
void gat_kernel(const float* __restrict__ x, const float* __restrict__ aw,
                const float* __restrict__ outb, const float* __restrict__ sqb,
                float* __restrict__ dout)
{
    __shared__ unsigned long long cand[Q][CAPQ];
    __shared__ int   nbr[Q][K];
    __shared__ float Tsh[Q][4];
    __shared__ int   cnt[Q];
    __shared__ float redv[4];
    __shared__ int   redi[4];

    const int tid  = threadIdx.x;
    const int lane = tid & 63;
    const int wave = tid >> 6;
    const int i0   = blockIdx.x * Q;

    // --- query features + sq -> SGPRs (block-uniform) ---
    float fi[Q][D], sqi[Q];
#pragma unroll
    for (int q = 0; q < Q; ++q) {
        const float* xq = x + (i0 + q) * 8;
        float4 a0 = *reinterpret_cast<const float4*>(xq);
        float4 a1 = *reinterpret_cast<const float4*>(xq + 4);
        fi[q][0] = rfl(a0.x); fi[q][1] = rfl(a0.y); fi[q][2] = rfl(a0.z);
        fi[q][3] = rfl(a0.w); fi[q][4] = rfl(a1.x); fi[q][5] = rfl(a1.y);
        fi[q][6] = rfl(a1.z);
        sqi[q]   = rfl(sqb[i0 + q]);
    }
    if (tid < Q) cnt[tid] = 0;

    const float* xt = x + tid * 8;
    const float* st = sqb + tid;

    // --- pass A: c in [0,16), distances kept in registers ---
    float dA[Q][HALF];
    float lmin[Q] = {INFINITY, INFINITY, INFINITY, INFINITY};
#pragma unroll
    for (int c = 0; c < HALF; ++c) {
        float4 b0 = *reinterpret_cast<const float4*>(xt + c * 2048);
        float4 b1 = *reinterpret_cast<const float4*>(xt + c * 2048 + 4);
        float sqj = st[c * 256];
        int j = tid + (c << 8);
#pragma unroll
        for (int q = 0; q < Q; ++q) {
            float dot = fi[q][0]*b0.x + fi[q][1]*b0.y + fi[q][2]*b0.z + fi[q][3]*b0.w
                      + fi[q][4]*b1.x + fi[q][5]*b1.y + fi[q][6]*b1.z;
            float d2 = fmaf(-2.0f, dot, sqi[q] + sqj);
            d2 = fmaxf(d2, 0.0f);
            d2 = (j == i0 + q) ? INFINITY : d2;
            dA[q][c] = d2;
            lmin[q] = fminf(lmin[q], d2);
        }
    }

    // --- per-wave ascending bitonic sort of 64 lane-minima; take pos 7.
    //     T_q = max over waves of pos-7  =>  >= 8 elements/wave <= T_q  => >=32 total.
#pragma unroll
    for (int q = 0; q < Q; ++q) {
        float v = lmin[q];
#pragma unroll
        for (int k = 2; k <= 64; k <<= 1) {
#pragma unroll
            for (int j = k >> 1; j > 0; j >>= 1) {
                float o  = __shfl_xor(v, j);
                bool up  = ((lane & k) == 0);
                bool lo  = ((lane & j) == 0);
                v = (lo == up) ? fminf(v, o) : fmaxf(v, o);
            }
        }
        float t = __shfl(v, 7);
        if (lane == 0) Tsh[q][wave] = t;
    }
    __syncthreads();

    float Tq[Q];
#pragma unroll
    for (int q = 0; q < Q; ++q)
        Tq[q] = fmaxf(fmaxf(Tsh[q][0], Tsh[q][1]), fmaxf(Tsh[q][2], Tsh[q][3]));

    // --- compact pass A survivors (ballot-aggregated LDS atomics) ---
#pragma unroll
    for (int c = 0; c < HALF; ++c) {
#pragma unroll
        for (int q = 0; q < Q; ++q) {
            float d = dA[q][c];
            if (d <= Tq[q]) {
                unsigned long long mk = __ballot(1);
                int prefix = __popcll(mk & ((1ull << lane) - 1ull));
                int base = 0;
                if (prefix == 0) base = atomicAdd(&cnt[q], (int)__popcll(mk));
                base = __shfl(base, (int)__ffsll(mk) - 1);
                int pos = base + prefix;
                if (pos < CAPQ)
                    cand[q][pos] = ((unsigned long long)__float_as_uint(d) << 32)
                                 | (unsigned)(tid + (c << 8));
            }
        }
    }

    // --- pass B: c in [16,32), stream + compact (no register storage) ---
#pragma unroll
    for (int c = HALF; c < CPT; ++c) {
        float4 b0 = *reinterpret_cast<const float4*>(xt + c * 2048);
        float4 b1 = *reinterpret_cast<const float4*>(xt + c * 2048 + 4);
        float sqj = st[c * 256];
        int j = tid + (c << 8);
#pragma unroll
        for (int q = 0; q < Q; ++q) {
            float dot = fi[q][0]*b0.x + fi[q][1]*b0.y + fi[q][2]*b0.z + fi[q][3]*b0.w
                      + fi[q][4]*b1.x + fi[q][5]*b1.y + fi[q][6]*b1.z;
            float d2 = fmaf(-2.0f, dot, sqi[q] + sqj);
            d2 = fmaxf(d2, 0.0f);
            d2 = (j == i0 + q) ? INFINITY : d2;
            if (d2 <= Tq[q]) {
                unsigned long long mk = __ballot(1);
                int prefix = __popcll(mk & ((1ull << lane) - 1ull));
                int base = 0;
                if (prefix == 0) base = atomicAdd(&cnt[q], (int)__popcll(mk));
                base = __shfl(base, (int)__ffsll(mk) - 1);
                int pos = base + prefix;
                if (pos < CAPQ)
                    cand[q][pos] = ((unsigned long long)__float_as_uint(d2) << 32)
                                 | (unsigned)j;
            }
        }
    }
    __syncthreads();

    // --- rank-by-counting selection: wave w handles query w ---
    {
        const int q  = wave;
        const int Mq = cnt[q];
        if (Mq <= CAPQ) {
            for (int p = lane; p < Mq; p += 64) {
                unsigned long long my = cand[q][p];
                int rank = 0;
                for (int m = 0; m < Mq; ++m)
                    rank += (cand[q][m] < my) ? 1 : 0;
                if (rank < K) nbr[q][rank] = (int)(my & 0xffffffffu);
            }
        }
    }
    __syncthreads();

    // --- exact fallback (cold, ~never): recompute-and-extract 32 sequentially ---
#pragma unroll
    for (int q = 0; q < Q; ++q) {
        if (cnt[q] > CAPQ) {                 // block-uniform condition
            float lastv = -1.0f; int lasti = -1;
            for (int it = 0; it < K; ++it) {
                float best = INFINITY; int bidx = 0x7fffffff;
#pragma unroll 1
                for (int c = 0; c < CPT; ++c) {
                    float4 b0 = *reinterpret_cast<const float4*>(xt + c * 2048);
                    float4 b1 = *reinterpret_cast<const float4*>(xt + c * 2048 + 4);
                    float sqj = st[c * 256];
                    int j = tid + (c << 8);
                    float dot = fi[q][0]*b0.x + fi[q][1]*b0.y + fi[q][2]*b0.z + fi[q][3]*b0.w
                              + fi[q][4]*b1.x + fi[q][5]*b1.y + fi[q][6]*b1.z;
                    float d2 = fmaf(-2.0f, dot, sqi[q] + sqj);
                    d2 = fmaxf(d2, 0.0f);
                    d2 = (j == i0 + q) ? INFINITY : d2;
                    bool gt = (d2 > lastv) || (d2 == lastv && j > lasti);
                    if (gt && (d2 < best || (d2 == best && j < bidx))) { best = d2; bidx = j; }
                }
#pragma unroll
                for (int off = 32; off > 0; off >>= 1) {
                    float ov = __shfl_down(best, off);
                    int   oi = __shfl_down(bidx, off);
                    if (ov < best || (ov == best && oi < bidx)) { best = ov; bidx = oi; }
                }
                if (lane == 0) { redv[wave] = best; redi[wave] = bidx; }
                __syncthreads();
                float bv = redv[0]; int bi = redi[0];
#pragma unroll
                for (int w = 1; w < 4; ++w)
                    if (redv[w] < bv || (redv[w] == bv && redi[w] < bi)) { bv = redv[w]; bi = redi[w]; }
                if (tid == 0) nbr[q][it] = bi;
                lastv = bv; lasti = bi;
                __syncthreads();
            }
        }
    }

    // --- attention epilogue: wave w handles query w, lanes 0..31 ---
    {
        const int q  = wave;
        const int iq = i0 + q;
        if (lane < K) {
            int nk = nbr[q][lane];
            float s = 0.f;
#pragma unroll
            for (int c = 0; c < D; ++c) s += outb[iq * D + c] * aw[c];
            float xp[D + 1];
#pragma unroll
            for (int c = 0; c < D; ++c) {
                float on = outb[nk * D + c];
                xp[c] = on;
                s += on * aw[D + c];
            }
            xp[D] = x[nk * 8 + 7];           // neighbor pollutant

            float m = s;
#pragma unroll
            for (int off = 16; off > 0; off >>= 1) m = fmaxf(m, __shfl_xor(m, off, 32));
            float e = expf(s - m);
            float sum = e;
#pragma unroll
            for (int off = 16; off > 0; off >>= 1) sum += __shfl_xor(sum, off, 32);
            float att = e / sum;

            float agg[D + 1];
#pragma unroll
            for (int dd = 0; dd < D + 1; ++dd) {
                float v = att * xp[dd];
#pragma unroll
                for (int off = 16; off > 0; off >>= 1) v += __shfl_xor(v, off, 32);
                agg[dd] = v;
            }

            if (lane < D) {
                float o = outb[iq * D + lane];
                dout[iq * 15 + lane] = o;
                dout[N_NODES * 15 + iq * 15 + lane] = o;
            }
            if (lane < D + 1) {
                float av_ = agg[0];
#pragma unroll
                for (int dd = 1; dd < D + 1; ++dd) av_ = (lane == dd) ? agg[dd] : av_;
                dout[iq * 15 + D + lane] = av_;
                dout[N_NODES * 15 + iq * 15 + D + lane] = av_;
            }
            if (iq == N_NODES - 1) dout[2 * N_NODES * 15 + lane] = att;
        }
    }
}

extern "C" void kernel_launch(void* const* d_in, const int* in_sizes, int n_in,
                              void* d_out, int out_size, void* d_ws, size_t ws_size,
                              hipStream_t stream) {
    (void)in_sizes; (void)n_in; (void)out_size; (void)ws_size;
    const float* x = (const float*)d_in[0];
    const float* W = (const float*)d_in[1];
    const float* a = (const float*)d_in[2];
    float* out  = (float*)d_out;
    float* outb = (float*)d_ws;                 // 8192*7 floats
    float* sqb  = outb + N_NODES * D;           // 8192 floats

    hipLaunchKernelGGL(precompute_kernel, dim3(N_NODES / NT), dim3(NT),
                       0, stream, x, W, outb, sqb);
    hipLaunchKernelGGL(gat_kernel, dim3(N_NODES / Q), dim3(NT),
                       0, stream, x, a, outb, sqb, out);
}

// Round 3
// 125.737 us; speedup vs baseline: 1.1463x; 1.1463x over previous
//
#include <hip/hip_runtime.h>
#include <math.h>
#include <stdint.h>

#define N_NODES 8192
#define D 7
#define K 32
#define NT 512
#define QB 8
#define CPT (N_NODES / NT)   // 16 j's per thread
#define CAPQ 256

typedef unsigned long long u64;

__device__ __forceinline__ float rfl(float v) {
    return __uint_as_float(__builtin_amdgcn_readfirstlane(__float_as_uint(v)));
}

// m = sqj - 2*dot(fi, fj). Identical rounding at every call site.
__device__ __forceinline__ float dist_m(const float4 b0, const float4 b1,
                                        float sqj, const float* fq) {
    float dot = fq[0] * b0.x;
    dot = fmaf(fq[1], b0.y, dot);
    dot = fmaf(fq[2], b0.z, dot);
    dot = fmaf(fq[3], b0.w, dot);
    dot = fmaf(fq[4], b1.x, dot);
    dot = fmaf(fq[5], b1.y, dot);
    dot = fmaf(fq[6], b1.z, dot);
    return fmaf(-2.0f, dot, sqj);
}

// ---------------------------------------------------------------------------
// Kernel 1: out = clip(feat @ W^T, -1, 1), sq = rowsum(feat^2)
// ---------------------------------------------------------------------------
__global__ __launch_bounds__(256)
void precompute_kernel(const float* __restrict__ x, const float* __restrict__ W,
                       float* __restrict__ outb, float* __restrict__ sqb)
{
    int n = blockIdx.x * 256 + threadIdx.x;
    float4 v0 = *reinterpret_cast<const float4*>(x + n * 8);
    float4 v1 = *reinterpret_cast<const float4*>(x + n * 8 + 4);
    float f[D] = {v0.x, v0.y, v0.z, v0.w, v1.x, v1.y, v1.z};
    float sq = 0.f;
#pragma unroll
    for (int c = 0; c < D; ++c) sq += f[c] * f[c];
    sqb[n] = sq;
#pragma unroll
    for (int r = 0; r < D; ++r) {
        float acc = 0.f;
#pragma unroll
        for (int c = 0; c < D; ++c) acc += f[c] * W[r * D + c];
        acc = fminf(fmaxf(acc, -1.f), 1.f);
        outb[n * D + r] = acc;
    }
}

// ---------------------------------------------------------------------------
// Kernel 2: exact top-32 (jax.lax.top_k order) + attention. QB=8 queries/block,
// 512 threads, two streaming passes (threshold, then compact), no dist cache.
// ---------------------------------------------------------------------------
__global__ __launch_bounds__(NT, 8)
void gat_kernel(const float* __restrict__ x, const float* __restrict__ aw,
                const float* __restrict__ outb, const float* __restrict__ sqb,
                float* __restrict__ dout)
{
    __shared__ u64   cand[QB][CAPQ];     // 16 KB
    __shared__ int   nbr[QB][K];
    __shared__ float Tsh[8][QB];         // [wave][q]
    __shared__ float Tfin[QB];
    __shared__ int   cnt[QB];
    __shared__ float redv[8];
    __shared__ int   redi[8];
    __shared__ float bcv;
    __shared__ int   bci;

    const int tid  = threadIdx.x;
    const int lane = tid & 63;
    const int wave = tid >> 6;
    const int i0   = blockIdx.x * QB;

    // query features + sq -> SGPRs
    float fi[QB][D], sqi[QB];
#pragma unroll
    for (int q = 0; q < QB; ++q) {
        const float* xq = x + (i0 + q) * 8;
        float4 a0 = *reinterpret_cast<const float4*>(xq);
        float4 a1 = *reinterpret_cast<const float4*>(xq + 4);
        fi[q][0] = rfl(a0.x); fi[q][1] = rfl(a0.y); fi[q][2] = rfl(a0.z);
        fi[q][3] = rfl(a0.w); fi[q][4] = rfl(a1.x); fi[q][5] = rfl(a1.y);
        fi[q][6] = rfl(a1.z);
        sqi[q]   = rfl(sqb[i0 + q]);
    }

    const float4* xb = reinterpret_cast<const float4*>(x);

    // ---- pass 1: lane-min of m per query (no diag check, no clamp) ----
    float lm[QB];
#pragma unroll
    for (int q = 0; q < QB; ++q) lm[q] = INFINITY;

#pragma unroll 4
    for (int c = 0; c < CPT; ++c) {
        int j = c * NT + tid;
        float4 b0 = xb[j * 2];
        float4 b1 = xb[j * 2 + 1];
        float sqj = sqb[j];
#pragma unroll
        for (int q = 0; q < QB; ++q)
            lm[q] = fminf(lm[q], dist_m(b0, b1, sqj, fi[q]));
    }

    // ---- per-wave bitonic sort of 64 lane-mins; pos 4 = 5th smallest.
    //      T[q] = max over 8 waves  =>  >= 8*(5-1) = 32 non-diag elems <= T.
#pragma unroll
    for (int q = 0; q < QB; ++q) {
        float v = lm[q];
#pragma unroll
        for (int k = 2; k <= 64; k <<= 1) {
#pragma unroll
            for (int j = k >> 1; j > 0; j >>= 1) {
                float o  = __shfl_xor(v, j);
                bool up  = ((lane & k) == 0);
                bool lo  = ((lane & j) == 0);
                v = (lo == up) ? fminf(v, o) : fmaxf(v, o);
            }
        }
        float t = __shfl(v, 4);
        if (lane == 0) Tsh[wave][q] = t;
    }
    __syncthreads();

    if (tid < QB) {                       // wave 0: reduce thresholds
        float mx = Tsh[0][tid];
#pragma unroll
        for (int w = 1; w < 8; ++w) mx = fmaxf(mx, Tsh[w][tid]);
        Tfin[tid] = mx;
    }
    if (tid >= 64 && tid < 64 + QB) cnt[tid - 64] = 0;   // wave 1: zero counts
    __syncthreads();

    float tmq[QB];
#pragma unroll
    for (int q = 0; q < QB; ++q)
        tmq[q] = fmaxf(Tfin[q], -sqi[q]);   // capture clamp-to-zero region

    // ---- pass 2: recompute, test, compact survivors ----
#pragma unroll 4
    for (int c = 0; c < CPT; ++c) {
        int j = c * NT + tid;
        float4 b0 = xb[j * 2];
        float4 b1 = xb[j * 2 + 1];
        float sqj = sqb[j];
#pragma unroll
        for (int q = 0; q < QB; ++q) {
            float m = dist_m(b0, b1, sqj, fi[q]);
            if (m <= tmq[q] && j != i0 + q) {
                float d2c = fmaxf(sqi[q] + m, 0.f);
                u64 key = ((u64)__float_as_uint(d2c) << 32) | (unsigned)j;
                u64 mk = __ballot(1);
                int px = __popcll(mk & ((1ull << lane) - 1ull));
                int base = 0;
                if (px == 0) base = atomicAdd(&cnt[q], (int)__popcll(mk));
                base = __shfl(base, (int)__ffsll(mk) - 1);
                int pos = base + px;
                if (pos < CAPQ) cand[q][pos] = key;
            }
        }
    }
    __syncthreads();

    // ---- selection: wave w handles query w, rank-by-counting ----
    {
        const int q = wave;
        const int M = cnt[q];
        if (M >= K && M <= CAPQ) {
            for (int p = lane; p < M; p += 64) {
                u64 my = cand[q][p];
                int rank = 0;
                for (int m = 0; m < M; ++m)
                    rank += (cand[q][m] < my) ? 1 : 0;
                if (rank < K) nbr[q][rank] = (int)(my & 0xffffffffu);
            }
        }
    }
    __syncthreads();

    // ---- exact fallback (cold): threshold failed for some query ----
#pragma unroll 1
    for (int q = 0; q < QB; ++q) {
        int M = cnt[q];                    // block-uniform
        if (M < K || M > CAPQ) {
            const int iq = i0 + q;
            float lastv = -1.0f; int lasti = -1;
#pragma unroll 1
            for (int it = 0; it < K; ++it) {
                float best = INFINITY; int bidx = 0x7fffffff;
#pragma unroll 1
                for (int c = 0; c < CPT; ++c) {
                    int j = c * NT + tid;
                    float4 b0 = xb[j * 2];
                    float4 b1 = xb[j * 2 + 1];
                    float m = dist_m(b0, b1, sqb[j], fi[q]);
                    float d2c = fmaxf(sqi[q] + m, 0.f);
                    if (j == iq) continue;
                    bool gt = (d2c > lastv) || (d2c == lastv && j > lasti);
                    if (gt && (d2c < best || (d2c == best && j < bidx))) {
                        best = d2c; bidx = j;
                    }
                }
#pragma unroll
                for (int off = 32; off > 0; off >>= 1) {
                    float ov = __shfl_down(best, off);
                    int   oi = __shfl_down(bidx, off);
                    if (ov < best || (ov == best && oi < bidx)) { best = ov; bidx = oi; }
                }
                if (lane == 0) { redv[wave] = best; redi[wave] = bidx; }
                __syncthreads();
                if (tid == 0) {
                    float bv = redv[0]; int bi = redi[0];
#pragma unroll
                    for (int w = 1; w < 8; ++w)
                        if (redv[w] < bv || (redv[w] == bv && redi[w] < bi)) {
                            bv = redv[w]; bi = redi[w];
                        }
                    bcv = bv; bci = bi;
                    nbr[q][it] = bi;
                }
                __syncthreads();
                lastv = bcv; lasti = bci;
            }
        }
    }
    __syncthreads();

    // ---- attention epilogue: wave w -> query w, lanes 0..31 ----
    {
        const int q  = wave;
        const int iq = i0 + q;
        if (lane < K) {
            int nk = nbr[q][lane];
            float s = 0.f;
#pragma unroll
            for (int c = 0; c < D; ++c) s += outb[iq * D + c] * aw[c];
            float xp[D + 1];
#pragma unroll
            for (int c = 0; c < D; ++c) {
                float on = outb[nk * D + c];
                xp[c] = on;
                s += on * aw[D + c];
            }
            xp[D] = x[nk * 8 + 7];

            float m = s;
#pragma unroll
            for (int off = 16; off > 0; off >>= 1) m = fmaxf(m, __shfl_xor(m, off, 32));
            float e = expf(s - m);
            float sum = e;
#pragma unroll
            for (int off = 16; off > 0; off >>= 1) sum += __shfl_xor(sum, off, 32);
            float att = e / sum;

            float agg[D + 1];
#pragma unroll
            for (int dd = 0; dd < D + 1; ++dd) {
                float v = att * xp[dd];
#pragma unroll
                for (int off = 16; off > 0; off >>= 1) v += __shfl_xor(v, off, 32);
                agg[dd] = v;
            }

            if (lane < D) {
                float o = outb[iq * D + lane];
                dout[iq * 15 + lane] = o;
                dout[N_NODES * 15 + iq * 15 + lane] = o;
            }
            if (lane < D + 1) {
                float av_ = agg[0];
#pragma unroll
                for (int dd = 1; dd < D + 1; ++dd) av_ = (lane == dd) ? agg[dd] : av_;
                dout[iq * 15 + D + lane] = av_;
                dout[N_NODES * 15 + iq * 15 + D + lane] = av_;
            }
            if (iq == N_NODES - 1) dout[2 * N_NODES * 15 + lane] = att;
        }
    }
}

extern "C" void kernel_launch(void* const* d_in, const int* in_sizes, int n_in,
                              void* d_out, int out_size, void* d_ws, size_t ws_size,
                              hipStream_t stream) {
    (void)in_sizes; (void)n_in; (void)out_size; (void)ws_size;
    const float* x = (const float*)d_in[0];
    const float* W = (const float*)d_in[1];
    const float* a = (const float*)d_in[2];
    float* out  = (float*)d_out;
    float* outb = (float*)d_ws;                 // 8192*7 floats
    float* sqb  = outb + N_NODES * D;           // 8192 floats

    hipLaunchKernelGGL(precompute_kernel, dim3(N_NODES / 256), dim3(256),
                       0, stream, x, W, outb, sqb);
    hipLaunchKernelGGL(gat_kernel, dim3(N_NODES / QB), dim3(NT),
                       0, stream, x, a, outb, sqb, out);
}

// Round 4
// 104.069 us; speedup vs baseline: 1.3850x; 1.2082x over previous
//
#include <hip/hip_runtime.h>
#include <math.h>
#include <stdint.h>

#define N_NODES 8192
#define D 7
#define K 32
#define NT 512
#define QB 8
#define CPT (N_NODES / NT)   // 16 j's per thread
#define CAPQ 256

typedef unsigned long long u64;

__device__ __forceinline__ float rfl(float v) {
    return __uint_as_float(__builtin_amdgcn_readfirstlane(__float_as_uint(v)));
}

// m = sqj - 2*dot(fi, fj). Identical rounding at every call site.
__device__ __forceinline__ float dist_m(const float4 b0, const float4 b1,
                                        float sqj, const float* fq) {
    float dot = fq[0] * b0.x;
    dot = fmaf(fq[1], b0.y, dot);
    dot = fmaf(fq[2], b0.z, dot);
    dot = fmaf(fq[3], b0.w, dot);
    dot = fmaf(fq[4], b1.x, dot);
    dot = fmaf(fq[5], b1.y, dot);
    dot = fmaf(fq[6], b1.z, dot);
    return fmaf(-2.0f, dot, sqj);
}

// ---------------------------------------------------------------------------
// Kernel 1: out = clip(feat @ W^T, -1, 1), sq = rowsum(feat^2)
// ---------------------------------------------------------------------------
__global__ __launch_bounds__(256)
void precompute_kernel(const float* __restrict__ x, const float* __restrict__ W,
                       float* __restrict__ outb, float* __restrict__ sqb)
{
    int n = blockIdx.x * 256 + threadIdx.x;
    float4 v0 = *reinterpret_cast<const float4*>(x + n * 8);
    float4 v1 = *reinterpret_cast<const float4*>(x + n * 8 + 4);
    float f[D] = {v0.x, v0.y, v0.z, v0.w, v1.x, v1.y, v1.z};
    float sq = 0.f;
#pragma unroll
    for (int c = 0; c < D; ++c) sq += f[c] * f[c];
    sqb[n] = sq;
#pragma unroll
    for (int r = 0; r < D; ++r) {
        float acc = 0.f;
#pragma unroll
        for (int c = 0; c < D; ++c) acc += f[c] * W[r * D + c];
        acc = fminf(fmaxf(acc, -1.f), 1.f);
        outb[n * D + r] = acc;
    }
}

// ---------------------------------------------------------------------------
// Kernel 2: exact top-32 (jax.lax.top_k order) + attention. QB=8 queries/block,
// 512 threads, two streaming passes (threshold, then compact), no dist cache.
// Register budget is the contract: unroll 2 keeps demand ~45-55 VGPR (no spill).
// ---------------------------------------------------------------------------
__global__ __launch_bounds__(NT, 6)
void gat_kernel(const float* __restrict__ x, const float* __restrict__ aw,
                const float* __restrict__ outb, const float* __restrict__ sqb,
                float* __restrict__ dout)
{
    __shared__ u64   cand[QB][CAPQ];     // 16 KB
    __shared__ int   nbr[QB][K];
    __shared__ float Tsh[8][QB];         // [wave][q]
    __shared__ float Tfin[QB];
    __shared__ int   cnt[QB];
    __shared__ float redv[8];
    __shared__ int   redi[8];
    __shared__ float bcv;
    __shared__ int   bci;

    const int tid  = threadIdx.x;
    const int lane = tid & 63;
    const int wave = tid >> 6;
    const int i0   = blockIdx.x * QB;

    // query features + sq -> SGPRs
    float fi[QB][D], sqi[QB];
#pragma unroll
    for (int q = 0; q < QB; ++q) {
        const float* xq = x + (i0 + q) * 8;
        float4 a0 = *reinterpret_cast<const float4*>(xq);
        float4 a1 = *reinterpret_cast<const float4*>(xq + 4);
        fi[q][0] = rfl(a0.x); fi[q][1] = rfl(a0.y); fi[q][2] = rfl(a0.z);
        fi[q][3] = rfl(a0.w); fi[q][4] = rfl(a1.x); fi[q][5] = rfl(a1.y);
        fi[q][6] = rfl(a1.z);
        sqi[q]   = rfl(sqb[i0 + q]);
    }

    const float4* xb = reinterpret_cast<const float4*>(x);

    // ---- pass 1: lane-min of m per query (no diag check, no clamp) ----
    float lm[QB];
#pragma unroll
    for (int q = 0; q < QB; ++q) lm[q] = INFINITY;

#pragma unroll 2
    for (int c = 0; c < CPT; ++c) {
        int j = c * NT + tid;
        float4 b0 = xb[j * 2];
        float4 b1 = xb[j * 2 + 1];
        float sqj = sqb[j];
#pragma unroll
        for (int q = 0; q < QB; ++q)
            lm[q] = fminf(lm[q], dist_m(b0, b1, sqj, fi[q]));
    }

    // ---- per-wave bitonic sort of 64 lane-mins; pos 4 = 5th smallest.
    //      T[q] = max over 8 waves  =>  >= 8*(5-1) = 32 non-diag elems <= T.
#pragma unroll
    for (int q = 0; q < QB; ++q) {
        float v = lm[q];
#pragma unroll
        for (int k = 2; k <= 64; k <<= 1) {
#pragma unroll
            for (int j = k >> 1; j > 0; j >>= 1) {
                float o  = __shfl_xor(v, j);
                bool up  = ((lane & k) == 0);
                bool lo  = ((lane & j) == 0);
                v = (lo == up) ? fminf(v, o) : fmaxf(v, o);
            }
        }
        float t = __shfl(v, 4);
        if (lane == 0) Tsh[wave][q] = t;
    }
    __syncthreads();

    if (tid < QB) {                       // wave 0: reduce thresholds
        float mx = Tsh[0][tid];
#pragma unroll
        for (int w = 1; w < 8; ++w) mx = fmaxf(mx, Tsh[w][tid]);
        Tfin[tid] = mx;
    }
    if (tid >= 64 && tid < 64 + QB) cnt[tid - 64] = 0;   // wave 1: zero counts
    __syncthreads();

    float tmq[QB];
#pragma unroll
    for (int q = 0; q < QB; ++q)
        tmq[q] = fmaxf(Tfin[q], -sqi[q]);   // capture clamp-to-zero region

    // ---- pass 2: recompute, test, compact survivors ----
#pragma unroll 2
    for (int c = 0; c < CPT; ++c) {
        int j = c * NT + tid;
        float4 b0 = xb[j * 2];
        float4 b1 = xb[j * 2 + 1];
        float sqj = sqb[j];
#pragma unroll
        for (int q = 0; q < QB; ++q) {
            float m = dist_m(b0, b1, sqj, fi[q]);
            if (m <= tmq[q] && j != i0 + q) {
                float d2c = fmaxf(sqi[q] + m, 0.f);
                u64 key = ((u64)__float_as_uint(d2c) << 32) | (unsigned)j;
                u64 mk = __ballot(1);
                int px = __popcll(mk & ((1ull << lane) - 1ull));
                int base = 0;
                if (px == 0) base = atomicAdd(&cnt[q], (int)__popcll(mk));
                base = __shfl(base, (int)__ffsll(mk) - 1);
                int pos = base + px;
                if (pos < CAPQ) cand[q][pos] = key;
            }
        }
    }
    __syncthreads();

    // ---- selection: wave w handles query w, rank-by-counting ----
    {
        const int q = wave;
        const int M = cnt[q];
        if (M >= K && M <= CAPQ) {
            for (int p = lane; p < M; p += 64) {
                u64 my = cand[q][p];
                int rank = 0;
                for (int m = 0; m < M; ++m)
                    rank += (cand[q][m] < my) ? 1 : 0;
                if (rank < K) nbr[q][rank] = (int)(my & 0xffffffffu);
            }
        }
    }
    __syncthreads();

    // ---- exact fallback (cold): threshold failed for some query ----
#pragma unroll 1
    for (int q = 0; q < QB; ++q) {
        int M = cnt[q];                    // block-uniform
        if (M < K || M > CAPQ) {
            const int iq = i0 + q;
            float lastv = -1.0f; int lasti = -1;
#pragma unroll 1
            for (int it = 0; it < K; ++it) {
                float best = INFINITY; int bidx = 0x7fffffff;
#pragma unroll 1
                for (int c = 0; c < CPT; ++c) {
                    int j = c * NT + tid;
                    float4 b0 = xb[j * 2];
                    float4 b1 = xb[j * 2 + 1];
                    float m = dist_m(b0, b1, sqb[j], fi[q]);
                    float d2c = fmaxf(sqi[q] + m, 0.f);
                    if (j == iq) continue;
                    bool gt = (d2c > lastv) || (d2c == lastv && j > lasti);
                    if (gt && (d2c < best || (d2c == best && j < bidx))) {
                        best = d2c; bidx = j;
                    }
                }
#pragma unroll
                for (int off = 32; off > 0; off >>= 1) {
                    float ov = __shfl_down(best, off);
                    int   oi = __shfl_down(bidx, off);
                    if (ov < best || (ov == best && oi < bidx)) { best = ov; bidx = oi; }
                }
                if (lane == 0) { redv[wave] = best; redi[wave] = bidx; }
                __syncthreads();
                if (tid == 0) {
                    float bv = redv[0]; int bi = redi[0];
#pragma unroll
                    for (int w = 1; w < 8; ++w)
                        if (redv[w] < bv || (redv[w] == bv && redi[w] < bi)) {
                            bv = redv[w]; bi = redi[w];
                        }
                    bcv = bv; bci = bi;
                    nbr[q][it] = bi;
                }
                __syncthreads();
                lastv = bcv; lasti = bci;
            }
        }
    }
    __syncthreads();

    // ---- attention epilogue: wave w -> query w, lanes 0..31 ----
    {
        const int q  = wave;
        const int iq = i0 + q;
        if (lane < K) {
            int nk = nbr[q][lane];
            float s = 0.f;
#pragma unroll
            for (int c = 0; c < D; ++c) s += outb[iq * D + c] * aw[c];
            float xp[D + 1];
#pragma unroll
            for (int c = 0; c < D; ++c) {
                float on = outb[nk * D + c];
                xp[c] = on;
                s += on * aw[D + c];
            }
            xp[D] = x[nk * 8 + 7];

            float m = s;
#pragma unroll
            for (int off = 16; off > 0; off >>= 1) m = fmaxf(m, __shfl_xor(m, off, 32));
            float e = expf(s - m);
            float sum = e;
#pragma unroll
            for (int off = 16; off > 0; off >>= 1) sum += __shfl_xor(sum, off, 32);
            float att = e / sum;

            float agg[D + 1];
#pragma unroll
            for (int dd = 0; dd < D + 1; ++dd) {
                float v = att * xp[dd];
#pragma unroll
                for (int off = 16; off > 0; off >>= 1) v += __shfl_xor(v, off, 32);
                agg[dd] = v;
            }

            if (lane < D) {
                float o = outb[iq * D + lane];
                dout[iq * 15 + lane] = o;
                dout[N_NODES * 15 + iq * 15 + lane] = o;
            }
            if (lane < D + 1) {
                float av_ = agg[0];
#pragma unroll
                for (int dd = 1; dd < D + 1; ++dd) av_ = (lane == dd) ? agg[dd] : av_;
                dout[iq * 15 + D + lane] = av_;
                dout[N_NODES * 15 + iq * 15 + D + lane] = av_;
            }
            if (iq == N_NODES - 1) dout[2 * N_NODES * 15 + lane] = att;
        }
    }
}

extern "C" void kernel_launch(void* const* d_in, const int* in_sizes, int n_in,
                              void* d_out, int out_size, void* d_ws, size_t ws_size,
                              hipStream_t stream) {
    (void)in_sizes; (void)n_in; (void)out_size; (void)ws_size;
    const float* x = (const float*)d_in[0];
    const float* W = (const float*)d_in[1];
    const float* a = (const float*)d_in[2];
    float* out  = (float*)d_out;
    float* outb = (float*)d_ws;                 // 8192*7 floats
    float* sqb  = outb + N_NODES * D;           // 8192 floats

    hipLaunchKernelGGL(precompute_kernel, dim3(N_NODES / 256), dim3(256),
                       0, stream, x, W, outb, sqb);
    hipLaunchKernelGGL(gat_kernel, dim3(N_NODES / QB), dim3(NT),
                       0, stream, x, a, outb, sqb, out);
}

// Round 5
// 92.923 us; speedup vs baseline: 1.5511x; 1.1199x over previous
//
#include <hip/hip_runtime.h>
#include <math.h>
#include <stdint.h>

#define N_NODES 8192
#define D 7
#define K 32
#define NT 512
#define QB 8
#define CPT (N_NODES / NT)   // 16 j's per thread
#define CAPQ 256

typedef unsigned long long u64;

__device__ __forceinline__ float rfl(float v) {
    return __uint_as_float(__builtin_amdgcn_readfirstlane(__float_as_uint(v)));
}

// m = sqj - 2*dot(fi, fj). float4s BY VALUE (no pointer -> SROA -> registers).
// B.w carries sq_i and is not part of the dot product.
__device__ __forceinline__ float dist_m(float4 b0, float4 b1, float sqj,
                                        float4 A, float4 B) {
    float dot = A.x * b0.x;
    dot = fmaf(A.y, b0.y, dot);
    dot = fmaf(A.z, b0.z, dot);
    dot = fmaf(A.w, b0.w, dot);
    dot = fmaf(B.x, b1.x, dot);
    dot = fmaf(B.y, b1.y, dot);
    dot = fmaf(B.z, b1.z, dot);
    return fmaf(-2.0f, dot, sqj);
}

// ---------------------------------------------------------------------------
// Kernel 1: out = clip(feat @ W^T, -1, 1), sq = rowsum(feat^2)
// ---------------------------------------------------------------------------
__global__ __launch_bounds__(256)
void precompute_kernel(const float* __restrict__ x, const float* __restrict__ W,
                       float* __restrict__ outb, float* __restrict__ sqb)
{
    int n = blockIdx.x * 256 + threadIdx.x;
    float4 v0 = *reinterpret_cast<const float4*>(x + n * 8);
    float4 v1 = *reinterpret_cast<const float4*>(x + n * 8 + 4);
    float f[D] = {v0.x, v0.y, v0.z, v0.w, v1.x, v1.y, v1.z};
    float sq = 0.f;
#pragma unroll
    for (int c = 0; c < D; ++c) sq += f[c] * f[c];
    sqb[n] = sq;
#pragma unroll
    for (int r = 0; r < D; ++r) {
        float acc = 0.f;
#pragma unroll
        for (int c = 0; c < D; ++c) acc += f[c] * W[r * D + c];
        acc = fminf(fmaxf(acc, -1.f), 1.f);
        outb[n * D + r] = acc;
    }
}

// ---------------------------------------------------------------------------
// Kernel 2: exact top-32 (jax.lax.top_k order) + attention. QB=8 queries/block,
// 512 threads, two streaming passes. Query features: float4 regs, ONLY
// statically indexed (rule #20) — the cold fallback reloads from global.
// ---------------------------------------------------------------------------
__global__ __launch_bounds__(NT, 4)
void gat_kernel(const float* __restrict__ x, const float* __restrict__ aw,
                const float* __restrict__ outb, const float* __restrict__ sqb,
                float* __restrict__ dout)
{
    __shared__ u64   cand[QB][CAPQ];     // 16 KB
    __shared__ int   nbr[QB][K];
    __shared__ float Tsh[8][QB];         // [wave][q]
    __shared__ float Tfin[QB];
    __shared__ int   cnt[QB];
    __shared__ float redv[8];
    __shared__ int   redi[8];
    __shared__ float bcv;
    __shared__ int   bci;

    const int tid  = threadIdx.x;
    const int lane = tid & 63;
    const int wave = tid >> 6;
    const int i0   = blockIdx.x * QB;

    // query features + sq -> uniform scalars (static indexing only!)
    float4 qA[QB], qBv[QB];
#pragma unroll
    for (int q = 0; q < QB; ++q) {
        const float* xq = x + (i0 + q) * 8;
        float4 a0 = *reinterpret_cast<const float4*>(xq);
        float4 a1 = *reinterpret_cast<const float4*>(xq + 4);
        qA[q].x  = rfl(a0.x); qA[q].y  = rfl(a0.y);
        qA[q].z  = rfl(a0.z); qA[q].w  = rfl(a0.w);
        qBv[q].x = rfl(a1.x); qBv[q].y = rfl(a1.y);
        qBv[q].z = rfl(a1.z); qBv[q].w = rfl(sqb[i0 + q]);   // sq_i
    }

    const float4* xb = reinterpret_cast<const float4*>(x);

    // ---- pass 1: lane-min of m per query (no diag check, no clamp) ----
    float lm[QB];
#pragma unroll
    for (int q = 0; q < QB; ++q) lm[q] = INFINITY;

#pragma unroll 2
    for (int c = 0; c < CPT; ++c) {
        int j = c * NT + tid;
        float4 b0 = xb[j * 2];
        float4 b1 = xb[j * 2 + 1];
        float sqj = sqb[j];
#pragma unroll
        for (int q = 0; q < QB; ++q)
            lm[q] = fminf(lm[q], dist_m(b0, b1, sqj, qA[q], qBv[q]));
    }

    // ---- per-wave bitonic sort of 64 lane-mins; pos 4 = 5th smallest.
    //      T[q] = max over 8 waves  =>  >= 8*(5-1) = 32 non-diag elems <= T.
#pragma unroll
    for (int q = 0; q < QB; ++q) {
        float v = lm[q];
#pragma unroll
        for (int k = 2; k <= 64; k <<= 1) {
#pragma unroll
            for (int j = k >> 1; j > 0; j >>= 1) {
                float o  = __shfl_xor(v, j);
                bool up  = ((lane & k) == 0);
                bool lo  = ((lane & j) == 0);
                v = (lo == up) ? fminf(v, o) : fmaxf(v, o);
            }
        }
        float t = __shfl(v, 4);
        if (lane == 0) Tsh[wave][q] = t;
    }
    __syncthreads();

    if (tid < QB) {                       // wave 0: reduce thresholds
        float mx = Tsh[0][tid];
#pragma unroll
        for (int w = 1; w < 8; ++w) mx = fmaxf(mx, Tsh[w][tid]);
        Tfin[tid] = mx;
    }
    if (tid >= 64 && tid < 64 + QB) cnt[tid - 64] = 0;   // wave 1: zero counts
    __syncthreads();

    float tmq[QB];
#pragma unroll
    for (int q = 0; q < QB; ++q)
        tmq[q] = fmaxf(Tfin[q], -qBv[q].w);   // capture clamp-to-zero region

    // ---- pass 2: recompute, test, compact survivors ----
#pragma unroll 2
    for (int c = 0; c < CPT; ++c) {
        int j = c * NT + tid;
        float4 b0 = xb[j * 2];
        float4 b1 = xb[j * 2 + 1];
        float sqj = sqb[j];
#pragma unroll
        for (int q = 0; q < QB; ++q) {
            float m = dist_m(b0, b1, sqj, qA[q], qBv[q]);
            if (m <= tmq[q] && j != i0 + q) {
                float d2c = fmaxf(qBv[q].w + m, 0.f);
                u64 key = ((u64)__float_as_uint(d2c) << 32) | (unsigned)j;
                u64 mk = __ballot(1);
                int px = __popcll(mk & ((1ull << lane) - 1ull));
                int base = 0;
                if (px == 0) base = atomicAdd(&cnt[q], (int)__popcll(mk));
                base = __shfl(base, (int)__ffsll(mk) - 1);
                int pos = base + px;
                if (pos < CAPQ) cand[q][pos] = key;
            }
        }
    }
    __syncthreads();

    // ---- selection: wave w handles query w, rank-by-counting ----
    {
        const int q = wave;
        const int M = cnt[q];
        if (M >= K && M <= CAPQ) {
            for (int p = lane; p < M; p += 64) {
                u64 my = cand[q][p];
                int rank = 0;
                for (int m = 0; m < M; ++m)
                    rank += (cand[q][m] < my) ? 1 : 0;
                if (rank < K) nbr[q][rank] = (int)(my & 0xffffffffu);
            }
        }
    }
    __syncthreads();

    // ---- exact fallback (cold): reloads query features from GLOBAL x ----
#pragma unroll 1
    for (int q = 0; q < QB; ++q) {
        int M = cnt[q];                    // block-uniform
        if (M < K || M > CAPQ) {
            const int iq = i0 + q;
            const float* xq = x + iq * 8;
            float4 A  = *reinterpret_cast<const float4*>(xq);
            float4 Bv = *reinterpret_cast<const float4*>(xq + 4);
            Bv.w = sqb[iq];                // sq_i (replaces pollutant slot)
            float lastv = -1.0f; int lasti = -1;
#pragma unroll 1
            for (int it = 0; it < K; ++it) {
                float best = INFINITY; int bidx = 0x7fffffff;
#pragma unroll 1
                for (int c = 0; c < CPT; ++c) {
                    int j = c * NT + tid;
                    float4 b0 = xb[j * 2];
                    float4 b1 = xb[j * 2 + 1];
                    float m = dist_m(b0, b1, sqb[j], A, Bv);
                    float d2c = fmaxf(Bv.w + m, 0.f);
                    if (j == iq) continue;
                    bool gt = (d2c > lastv) || (d2c == lastv && j > lasti);
                    if (gt && (d2c < best || (d2c == best && j < bidx))) {
                        best = d2c; bidx = j;
                    }
                }
#pragma unroll
                for (int off = 32; off > 0; off >>= 1) {
                    float ov = __shfl_down(best, off);
                    int   oi = __shfl_down(bidx, off);
                    if (ov < best || (ov == best && oi < bidx)) { best = ov; bidx = oi; }
                }
                if (lane == 0) { redv[wave] = best; redi[wave] = bidx; }
                __syncthreads();
                if (tid == 0) {
                    float bv = redv[0]; int bi = redi[0];
#pragma unroll
                    for (int w = 1; w < 8; ++w)
                        if (redv[w] < bv || (redv[w] == bv && redi[w] < bi)) {
                            bv = redv[w]; bi = redi[w];
                        }
                    bcv = bv; bci = bi;
                    nbr[q][it] = bi;
                }
                __syncthreads();
                lastv = bcv; lasti = bci;
            }
        }
    }
    __syncthreads();

    // ---- attention epilogue: wave w -> query w, lanes 0..31 ----
    {
        const int q  = wave;
        const int iq = i0 + q;
        if (lane < K) {
            int nk = nbr[q][lane];
            float s = 0.f;
#pragma unroll
            for (int c = 0; c < D; ++c) s += outb[iq * D + c] * aw[c];
            float xp[D + 1];
#pragma unroll
            for (int c = 0; c < D; ++c) {
                float on = outb[nk * D + c];
                xp[c] = on;
                s += on * aw[D + c];
            }
            xp[D] = x[nk * 8 + 7];

            float m = s;
#pragma unroll
            for (int off = 16; off > 0; off >>= 1) m = fmaxf(m, __shfl_xor(m, off, 32));
            float e = expf(s - m);
            float sum = e;
#pragma unroll
            for (int off = 16; off > 0; off >>= 1) sum += __shfl_xor(sum, off, 32);
            float att = e / sum;

            float agg[D + 1];
#pragma unroll
            for (int dd = 0; dd < D + 1; ++dd) {
                float v = att * xp[dd];
#pragma unroll
                for (int off = 16; off > 0; off >>= 1) v += __shfl_xor(v, off, 32);
                agg[dd] = v;
            }

            if (lane < D) {
                float o = outb[iq * D + lane];
                dout[iq * 15 + lane] = o;
                dout[N_NODES * 15 + iq * 15 + lane] = o;
            }
            if (lane < D + 1) {
                float av_ = agg[0];
#pragma unroll
                for (int dd = 1; dd < D + 1; ++dd) av_ = (lane == dd) ? agg[dd] : av_;
                dout[iq * 15 + D + lane] = av_;
                dout[N_NODES * 15 + iq * 15 + D + lane] = av_;
            }
            if (iq == N_NODES - 1) dout[2 * N_NODES * 15 + lane] = att;
        }
    }
}

extern "C" void kernel_launch(void* const* d_in, const int* in_sizes, int n_in,
                              void* d_out, int out_size, void* d_ws, size_t ws_size,
                              hipStream_t stream) {
    (void)in_sizes; (void)n_in; (void)out_size; (void)ws_size;
    const float* x = (const float*)d_in[0];
    const float* W = (const float*)d_in[1];
    const float* a = (const float*)d_in[2];
    float* out  = (float*)d_out;
    float* outb = (float*)d_ws;                 // 8192*7 floats
    float* sqb  = outb + N_NODES * D;           // 8192 floats

    hipLaunchKernelGGL(precompute_kernel, dim3(N_NODES / 256), dim3(256),
                       0, stream, x, W, outb, sqb);
    hipLaunchKernelGGL(gat_kernel, dim3(N_NODES / QB), dim3(NT),
                       0, stream, x, a, outb, sqb, out);
}

// Round 6
// 89.137 us; speedup vs baseline: 1.6170x; 1.0425x over previous
//
#include <hip/hip_runtime.h>
#include <math.h>
#include <stdint.h>

#define N_NODES 8192
#define D 7
#define K 32
#define NT 512
#define QB 8
#define CPT (N_NODES / NT)   // 16 j's per thread
#define ECAP 256             // per-query survivor capacity
#define DELTA 0.125f         // f16-screen error bound (analytic bound ~0.06)

typedef unsigned long long u64;
typedef _Float16 h2 __attribute__((ext_vector_type(2)));

__device__ __forceinline__ float rfl(float v) {
    return __uint_as_float(__builtin_amdgcn_readfirstlane(__float_as_uint(v)));
}
__device__ __forceinline__ unsigned rflu(unsigned v) {
    return __builtin_amdgcn_readfirstlane(v);
}
__device__ __forceinline__ h2 h2u(unsigned u) {
    union { unsigned u; h2 h; } t; t.u = u; return t.h;
}
__device__ __forceinline__ unsigned pkh(float a, float b) {
    union { h2 h; unsigned u; } t;
    t.h[0] = (_Float16)a; t.h[1] = (_Float16)b; return t.u;
}

#if __has_builtin(__builtin_amdgcn_fdot2)
#define FDOT2(a, b, c) __builtin_amdgcn_fdot2((a), (b), (c), false)
#else
__device__ __forceinline__ float FDOT2(h2 a, h2 b, float c) {
    return fmaf((float)a[1], (float)b[1], fmaf((float)a[0], (float)b[0], c));
}
#endif

// exact m = sqj - 2*dot(fi, fj); identical rounding chain at every call site.
// B.w carries sq_i (not part of the dot).
__device__ __forceinline__ float dist_m(float4 b0, float4 b1, float sqj,
                                        float4 A, float4 B) {
    float dot = A.x * b0.x;
    dot = fmaf(A.y, b0.y, dot);
    dot = fmaf(A.z, b0.z, dot);
    dot = fmaf(A.w, b0.w, dot);
    dot = fmaf(B.x, b1.x, dot);
    dot = fmaf(B.y, b1.y, dot);
    dot = fmaf(B.z, b1.z, dot);
    return fmaf(-2.0f, dot, sqj);
}

// ---------------------------------------------------------------------------
// Kernel 1: out = clip(feat @ W^T, -1, 1), sq = rowsum(feat^2),
//           packed f16 row [f0..f6, sq] (16 B/node) for the dot2 screen.
// ---------------------------------------------------------------------------
__global__ __launch_bounds__(256)
void precompute_kernel(const float* __restrict__ x, const float* __restrict__ W,
                       float* __restrict__ outb, float* __restrict__ sqb,
                       uint4* __restrict__ fh)
{
    int n = blockIdx.x * 256 + threadIdx.x;
    float4 v0 = *reinterpret_cast<const float4*>(x + n * 8);
    float4 v1 = *reinterpret_cast<const float4*>(x + n * 8 + 4);
    float f[D] = {v0.x, v0.y, v0.z, v0.w, v1.x, v1.y, v1.z};
    float sq = 0.f;
#pragma unroll
    for (int c = 0; c < D; ++c) sq += f[c] * f[c];
    sqb[n] = sq;
    uint4 h;
    h.x = pkh(f[0], f[1]); h.y = pkh(f[2], f[3]);
    h.z = pkh(f[4], f[5]); h.w = pkh(f[6], sq);
    fh[n] = h;
#pragma unroll
    for (int r = 0; r < D; ++r) {
        float acc = 0.f;
#pragma unroll
        for (int c = 0; c < D; ++c) acc += f[c] * W[r * D + c];
        acc = fminf(fmaxf(acc, -1.f), 1.f);
        outb[n * D + r] = acc;
    }
}

// ---------------------------------------------------------------------------
// Kernel 2: exact top-32 (jax.lax.top_k order) + attention.
// f16-dot2 screen passes -> dense exact fp32 phase -> rank-by-count.
// ---------------------------------------------------------------------------
__global__ __launch_bounds__(NT, 4)
void gat_kernel(const float* __restrict__ x, const float* __restrict__ aw,
                const float* __restrict__ outb, const float* __restrict__ sqb,
                const uint4* __restrict__ fh, float* __restrict__ dout)
{
    __shared__ u64   cand[QB][ECAP];   // 16 KB: exact (dist,idx) keys
    __shared__ int   ent[QB][ECAP];    // 8 KB: screen-survivor j's
    __shared__ int   nbr[QB][K];
    __shared__ float Tsh[8][QB];
    __shared__ float Tfin[QB];
    __shared__ int   scnt[QB];
    __shared__ int   cnt2[QB];
    __shared__ float qf[QB][8];        // exact f32 query feats + sqi
    __shared__ float redv[8];
    __shared__ int   redi[8];
    __shared__ float bcv;
    __shared__ int   bci;

    const int tid  = threadIdx.x;
    const int lane = tid & 63;
    const int wave = tid >> 6;
    const int i0   = blockIdx.x * QB;

    // packed screen-query scalars (SGPR; static indexing only)
    unsigned qs0[QB], qs1[QB], qs2[QB], qs3[QB];
    float sqi[QB];
#pragma unroll
    for (int q = 0; q < QB; ++q) {
        const float* xq = x + (i0 + q) * 8;
        float4 a0 = *reinterpret_cast<const float4*>(xq);
        float4 a1 = *reinterpret_cast<const float4*>(xq + 4);
        qs0[q] = rflu(pkh(-2.f * a0.x, -2.f * a0.y));
        qs1[q] = rflu(pkh(-2.f * a0.z, -2.f * a0.w));
        qs2[q] = rflu(pkh(-2.f * a1.x, -2.f * a1.y));
        qs3[q] = rflu(pkh(-2.f * a1.z, 1.0f));
        sqi[q] = rfl(sqb[i0 + q]);
    }
    if (tid < QB) {
        const float* xq = x + (i0 + tid) * 8;
#pragma unroll
        for (int c = 0; c < D; ++c) qf[tid][c] = xq[c];
        qf[tid][7] = sqb[i0 + tid];
        scnt[tid] = 0;
        cnt2[tid] = 0;
    }

    // ---- pass 1: f16-dot2 screen, lane-min per query ----
    float lm[QB];
#pragma unroll
    for (int q = 0; q < QB; ++q) lm[q] = INFINITY;

#pragma unroll 2
    for (int c = 0; c < CPT; ++c) {
        uint4 dj = fh[c * NT + tid];
#pragma unroll
        for (int q = 0; q < QB; ++q) {
            float m = FDOT2(h2u(dj.x), h2u(qs0[q]),
                      FDOT2(h2u(dj.y), h2u(qs1[q]),
                      FDOT2(h2u(dj.z), h2u(qs2[q]),
                      FDOT2(h2u(dj.w), h2u(qs3[q]), 0.f))));
            lm[q] = fminf(lm[q], m);
        }
    }

    // ---- per-wave bitonic sort of 64 lane-mins; pos 4 = 5th smallest.
    //      >= 8*5 = 40 screen values <= T_scr (>=39 non-diag >= 33 needed).
#pragma unroll
    for (int q = 0; q < QB; ++q) {
        float v = lm[q];
#pragma unroll
        for (int k = 2; k <= 64; k <<= 1) {
#pragma unroll
            for (int j = k >> 1; j > 0; j >>= 1) {
                float o  = __shfl_xor(v, j);
                bool up  = ((lane & k) == 0);
                bool lo  = ((lane & j) == 0);
                v = (lo == up) ? fminf(v, o) : fmaxf(v, o);
            }
        }
        float t = __shfl(v, 4);
        if (lane == 0) Tsh[wave][q] = t;
    }
    __syncthreads();

    if (tid < QB) {
        float mx = Tsh[0][tid];
#pragma unroll
        for (int w = 1; w < 8; ++w) mx = fmaxf(mx, Tsh[w][tid]);
        Tfin[tid] = mx;
    }
    __syncthreads();

    // screen-keep threshold: covers exact top-32 (+2*delta) and clamp-to-zero ties
    float kthr[QB];
#pragma unroll
    for (int q = 0; q < QB; ++q)
        kthr[q] = fmaxf(Tfin[q] + 2.f * DELTA, -sqi[q] + DELTA);

    // ---- pass 2: f16-dot2 recompute, compact survivor j's (plain atomics) ----
#pragma unroll 2
    for (int c = 0; c < CPT; ++c) {
        int j = c * NT + tid;
        uint4 dj = fh[j];
#pragma unroll
        for (int q = 0; q < QB; ++q) {
            float m = FDOT2(h2u(dj.x), h2u(qs0[q]),
                      FDOT2(h2u(dj.y), h2u(qs1[q]),
                      FDOT2(h2u(dj.z), h2u(qs2[q]),
                      FDOT2(h2u(dj.w), h2u(qs3[q]), 0.f))));
            if (m <= kthr[q] && j != i0 + q) {
                int p = atomicAdd(&scnt[q], 1);
                if (p < ECAP) ent[q][p] = j;
            }
        }
    }
    __syncthreads();

    // ---- dense exact fp32 phase: all threads over all survivor lists ----
    const float4* xb = reinterpret_cast<const float4*>(x);
#pragma unroll 1
    for (int q = 0; q < QB; ++q) {
        int n = scnt[q];
        if (n > ECAP) n = ECAP;
        for (int t = tid; t < n; t += NT) {
            int j = ent[q][t];
            float4 b0 = xb[j * 2];
            float4 b1 = xb[j * 2 + 1];
            float sqj = sqb[j];
            float4 A  = *reinterpret_cast<const float4*>(&qf[q][0]);
            float4 Bv = *reinterpret_cast<const float4*>(&qf[q][4]);  // .w = sqi
            float m   = dist_m(b0, b1, sqj, A, Bv);
            float d2c = fmaxf(Bv.w + m, 0.f);
            u64 key = ((u64)__float_as_uint(d2c) << 32) | (unsigned)j;
            cand[q][atomicAdd(&cnt2[q], 1)] = key;
        }
    }
    __syncthreads();

    // ---- selection: wave w -> query w, exact rank-by-counting ----
    {
        const int q = wave;
        const int s = scnt[q];
        if (s >= K && s <= ECAP) {
            const int M = cnt2[q];
            for (int p = lane; p < M; p += 64) {
                u64 my = cand[q][p];
                int rank = 0;
                for (int m = 0; m < M; ++m)
                    rank += (cand[q][m] < my) ? 1 : 0;
                if (rank < K) nbr[q][rank] = (int)(my & 0xffffffffu);
            }
        }
    }
    __syncthreads();

    // ---- exact fallback (cold): screen failed for some query ----
#pragma unroll 1
    for (int q = 0; q < QB; ++q) {
        int s = scnt[q];                   // block-uniform
        if (s < K || s > ECAP) {
            const int iq = i0 + q;
            const float* xq = x + iq * 8;
            float4 A  = *reinterpret_cast<const float4*>(xq);
            float4 Bv = *reinterpret_cast<const float4*>(xq + 4);
            Bv.w = sqb[iq];
            float lastv = -1.0f; int lasti = -1;
#pragma unroll 1
            for (int it = 0; it < K; ++it) {
                float best = INFINITY; int bidx = 0x7fffffff;
#pragma unroll 1
                for (int c = 0; c < CPT; ++c) {
                    int j = c * NT + tid;
                    float4 b0 = xb[j * 2];
                    float4 b1 = xb[j * 2 + 1];
                    float m = dist_m(b0, b1, sqb[j], A, Bv);
                    float d2c = fmaxf(Bv.w + m, 0.f);
                    if (j == iq) continue;
                    bool gt = (d2c > lastv) || (d2c == lastv && j > lasti);
                    if (gt && (d2c < best || (d2c == best && j < bidx))) {
                        best = d2c; bidx = j;
                    }
                }
#pragma unroll
                for (int off = 32; off > 0; off >>= 1) {
                    float ov = __shfl_down(best, off);
                    int   oi = __shfl_down(bidx, off);
                    if (ov < best || (ov == best && oi < bidx)) { best = ov; bidx = oi; }
                }
                if (lane == 0) { redv[wave] = best; redi[wave] = bidx; }
                __syncthreads();
                if (tid == 0) {
                    float bv = redv[0]; int bi = redi[0];
#pragma unroll
                    for (int w = 1; w < 8; ++w)
                        if (redv[w] < bv || (redv[w] == bv && redi[w] < bi)) {
                            bv = redv[w]; bi = redi[w];
                        }
                    bcv = bv; bci = bi;
                    nbr[q][it] = bi;
                }
                __syncthreads();
                lastv = bcv; lasti = bci;
            }
        }
    }
    __syncthreads();

    // ---- attention epilogue: wave w -> query w, lanes 0..31 ----
    {
        const int q  = wave;
        const int iq = i0 + q;
        if (lane < K) {
            int nk = nbr[q][lane];
            float s = 0.f;
#pragma unroll
            for (int c = 0; c < D; ++c) s += outb[iq * D + c] * aw[c];
            float xp[D + 1];
#pragma unroll
            for (int c = 0; c < D; ++c) {
                float on = outb[nk * D + c];
                xp[c] = on;
                s += on * aw[D + c];
            }
            xp[D] = x[nk * 8 + 7];

            float m = s;
#pragma unroll
            for (int off = 16; off > 0; off >>= 1) m = fmaxf(m, __shfl_xor(m, off, 32));
            float e = expf(s - m);
            float sum = e;
#pragma unroll
            for (int off = 16; off > 0; off >>= 1) sum += __shfl_xor(sum, off, 32);
            float att = e / sum;

            float agg[D + 1];
#pragma unroll
            for (int dd = 0; dd < D + 1; ++dd) {
                float v = att * xp[dd];
#pragma unroll
                for (int off = 16; off > 0; off >>= 1) v += __shfl_xor(v, off, 32);
                agg[dd] = v;
            }

            if (lane < D) {
                float o = outb[iq * D + lane];
                dout[iq * 15 + lane] = o;
                dout[N_NODES * 15 + iq * 15 + lane] = o;
            }
            if (lane < D + 1) {
                float av_ = agg[0];
#pragma unroll
                for (int dd = 1; dd < D + 1; ++dd) av_ = (lane == dd) ? agg[dd] : av_;
                dout[iq * 15 + D + lane] = av_;
                dout[N_NODES * 15 + iq * 15 + D + lane] = av_;
            }
            if (iq == N_NODES - 1) dout[2 * N_NODES * 15 + lane] = att;
        }
    }
}

extern "C" void kernel_launch(void* const* d_in, const int* in_sizes, int n_in,
                              void* d_out, int out_size, void* d_ws, size_t ws_size,
                              hipStream_t stream) {
    (void)in_sizes; (void)n_in; (void)out_size; (void)ws_size;
    const float* x = (const float*)d_in[0];
    const float* W = (const float*)d_in[1];
    const float* a = (const float*)d_in[2];
    float* out  = (float*)d_out;
    float* outb = (float*)d_ws;                       // 8192*7 f32
    float* sqb  = outb + N_NODES * D;                 // 8192 f32
    uint4* fh   = (uint4*)(sqb + N_NODES);            // 8192 * 16 B (16B-aligned)

    hipLaunchKernelGGL(precompute_kernel, dim3(N_NODES / 256), dim3(256),
                       0, stream, x, W, outb, sqb, fh);
    hipLaunchKernelGGL(gat_kernel, dim3(N_NODES / QB), dim3(NT),
                       0, stream, x, a, outb, sqb, fh, out);
}